// Round 6
// baseline (190.775 us; speedup 1.0000x reference)
//
#include <hip/hip_runtime.h>
#include <math.h>

#define BB 16
#define VV 778
#define OO 8192
#define GG 32
#define KNN 5
#define THREE_LOG2PI 5.513631199228036f
#define TSCAN 832   // 13 waves x 1 slot (R2's best-measured shape)

#define MED3 __builtin_amdgcn_fmed3f

typedef int i4v __attribute__((ext_vector_type(4)));

// sorted ascending insert: t[j] = min(t[j], max(t[j-1], s)) == med3(s, t[j-1], t[j])
__device__ __forceinline__ void insert5_med3(float (&t)[KNN], float s) {
    t[4] = MED3(s, t[3], t[4]);
    t[3] = MED3(s, t[2], t[3]);
    t[2] = MED3(s, t[1], t[2]);
    t[1] = MED3(s, t[0], t[1]);
    t[0] = fminf(t[0], s);
}

// merge sorted ascending b[5] into sorted ascending m[5]: 15 ops
__device__ __forceinline__ void merge5_med3(float (&m)[KNN], const float (&b)[KNN]) {
    m[4] = MED3(b[0], m[3], m[4]);
    m[3] = MED3(b[0], m[2], m[3]);
    m[2] = MED3(b[0], m[1], m[2]);
    m[1] = MED3(b[0], m[0], m[1]);
    m[0] = fminf(m[0], b[0]);
    m[4] = MED3(b[1], m[3], m[4]);
    m[3] = MED3(b[1], m[2], m[3]);
    m[2] = MED3(b[1], m[1], m[2]);
    m[1] = fminf(m[1], b[1]);
    m[4] = MED3(b[2], m[3], m[4]);
    m[3] = MED3(b[2], m[2], m[3]);
    m[2] = fminf(m[2], b[2]);
    m[4] = MED3(b[3], m[3], m[4]);
    m[3] = fminf(m[3], b[3]);
    m[4] = fminf(m[4], b[4]);
}

// monotone float->uint key: a<b <=> fkey(a)<fkey(b)
__device__ __forceinline__ unsigned int fkey(float s) {
    unsigned int u = __float_as_uint(s);
    unsigned int m = (u & 0x80000000u) ? 0xFFFFFFFFu : 0x80000000u;
    return u ^ m;
}

// one point: d2 = |q - v|^2, insert into top-5. px/py/pz are SGPR values
// (each v_sub reads exactly 1 SGPR - legal); fmas are VGPR-only.
__device__ __forceinline__ void dist_insert(float (&t)[KNN], float px, float py,
                                            float pz, float vx, float vy, float vz) {
    float dx = px - vx, dy = py - vy, dz = pz - vz;
    float d2 = fmaf(dx, dx, fmaf(dy, dy, dz * dz));
    insert5_med3(t, d2);
}

// ---------------- Kernel A: two block families, 832 thr x 1 vertex slot ----
// R5: R0-R4 established neither VALU nor LDS saturates - operand DELIVERY
// (LDS b128 broadcast x13 waves, or per-lane VMEM in R3) is the tax.
// Points are block-uniform -> force true SMEM via inline-asm s_load_dwordx4
// (R3's compiler-scalarization failed; asm cannot). No LDS staging, no
// inner-loop barriers. d2 = |q-v|^2 per lane (6 VALU) replaces the staged
// |q|^2 broadcast; same ordering (differs by per-vertex constant), finalize
// drops the +vv term to match.
template <int LOGP>
__global__ __launch_bounds__(TSCAN) void scan_kernel(
    const float* __restrict__ verts,
    const float* __restrict__ anchor_verts,
    const float* __restrict__ obj_pts,
    const float* __restrict__ contact_gaussians,
    const float* __restrict__ obj_normals,
    const float* __restrict__ init_verts,
    const float* __restrict__ init_anchors,
    int* __restrict__ gid_ws,
    float* __restrict__ active_ws,
    float* __restrict__ segmn,
    float* __restrict__ segmx,
    float* __restrict__ w_ws,
    float* __restrict__ top5,                 // [B][P][KNN][VV]  (d^2 values)
    unsigned long long* __restrict__ pmin,    // [B][P][VV] (fkey<<32)|idx
    float* __restrict__ out) {
    constexpr int P = 1 << LOGP;
    constexpr int NPTS = OO >> LOGP;

    __shared__ float anc[GG * 4];
    __shared__ float cholb[GG * 10];
    __shared__ unsigned short gidl[VV];
    __shared__ unsigned int smn[GG], smx[GG];

    int tid = threadIdx.x;
    int bid = blockIdx.x;

    if (bid < BB * P) {
        // ================= Family 1: KNN top-5 =============================
        int p = bid & (P - 1);
        int b = bid >> LOGP;

        bool valid = tid < VV;
        int vc = valid ? tid : (VV - 1);
        float vx, vy, vz;
        {
            const float* vp = verts + ((size_t)b * VV + vc) * 3;
            vx = vp[0]; vy = vp[1]; vz = vp[2];
        }

        float t[KNN];
#pragma unroll
        for (int k = 0; k < KNN; ++k) t[k] = INFINITY;

        unsigned long long addr =
            (unsigned long long)(obj_pts + ((size_t)b * OO + (size_t)p * NPTS) * 3);
#pragma unroll 2
        for (int i = 0; i < NPTS; i += 4) {
            i4v qa, qb, qc;   // 4 points = 48 B = 3x s_load_dwordx4 (SMEM, K$)
            asm volatile(
                "s_load_dwordx4 %0, %3, 0x0\n"
                "s_load_dwordx4 %1, %3, 0x10\n"
                "s_load_dwordx4 %2, %3, 0x20\n"
                "s_waitcnt lgkmcnt(0)\n"
                : "=&s"(qa), "=&s"(qb), "=&s"(qc)
                : "s"(addr));
            dist_insert(t, __int_as_float(qa.x), __int_as_float(qa.y),
                        __int_as_float(qa.z), vx, vy, vz);
            dist_insert(t, __int_as_float(qa.w), __int_as_float(qb.x),
                        __int_as_float(qb.y), vx, vy, vz);
            dist_insert(t, __int_as_float(qb.z), __int_as_float(qb.w),
                        __int_as_float(qc.x), vx, vy, vz);
            dist_insert(t, __int_as_float(qc.y), __int_as_float(qc.z),
                        __int_as_float(qc.w), vx, vy, vz);
            addr += 48;
        }
        if (valid) {
            size_t base = ((size_t)(b * P + p) * KNN) * VV + tid;
#pragma unroll
            for (int k = 0; k < KNN; ++k)
                top5[base + (size_t)k * VV] = t[k];
        }
        return;
    }

    // ================= Family 2: NN argmin (+ duties) ======================
    {
        int sub = bid - BB * P;
        int p = sub & (P - 1);
        int b = sub >> LOGP;

        bool wduty = (p == 0);                    // 16 blocks, one per b
        bool aduty = (p == 1 && b == 0);          // 1 block
        if (wduty || aduty) {
            if (tid < GG) {
                float x = init_anchors[tid * 3 + 0];
                float y = init_anchors[tid * 3 + 1];
                float z = init_anchors[tid * 3 + 2];
                anc[tid * 4 + 0] = x; anc[tid * 4 + 1] = y;
                anc[tid * 4 + 2] = z; anc[tid * 4 + 3] = x * x + y * y + z * z;
                smn[tid] = 0x7F800000u;
                smx[tid] = 0u;
                if (wduty) {
                    const float* cg2 = contact_gaussians + ((size_t)b * GG + tid) * 12;
                    const float* av = anchor_verts + ((size_t)b * GG + tid) * 3;
                    float c00 = cg2[3];
                    float c10 = cg2[6], c11 = cg2[7];
                    float c20 = cg2[9], c21 = cg2[10], c22 = cg2[11];
                    float L00 = sqrtf(c00);
                    float L10 = c10 / L00;
                    float L20 = c20 / L00;
                    float L11 = sqrtf(c11 - L10 * L10);
                    float L21 = (c21 - L20 * L10) / L11;
                    float L22 = sqrtf(c22 - L20 * L20 - L21 * L21);
                    float* c = cholb + tid * 10;
                    c[0] = L00; c[1] = L10; c[2] = L11;
                    c[3] = L20; c[4] = L21; c[5] = L22;
                    c[6] = logf(L00) + logf(L11) + logf(L22);
                    c[7] = cg2[0] + av[0];
                    c[8] = cg2[1] + av[1];
                    c[9] = cg2[2] + av[2];
                }
            }
            __syncthreads();
            for (int v = tid; v < VV; v += TSCAN) {
                float x = init_verts[v * 3 + 0];
                float y = init_verts[v * 3 + 1];
                float z = init_verts[v * 3 + 2];
                float vv = x * x + y * y + z * z;
                float best = INFINITY;
                int bg = 0;
                for (int g = 0; g < GG; ++g) {
                    float d2 = vv + anc[g * 4 + 3] -
                               2.0f * (x * anc[g * 4 + 0] + y * anc[g * 4 + 1] + z * anc[g * 4 + 2]);
                    d2 = fmaxf(d2, 0.0f);
                    if (d2 < best) { best = d2; bg = g; }
                }
                gidl[v] = (unsigned short)bg;
                if (aduty) gid_ws[v] = bg;
            }
            __syncthreads();
            if (wduty) {
                for (int v = tid; v < VV; v += TSCAN) {
                    int g = gidl[v];
                    const float* c = cholb + g * 10;
                    const float* vp = verts + ((size_t)b * VV + v) * 3;
                    float d0 = vp[0] - c[7];
                    float d1 = vp[1] - c[8];
                    float d2 = vp[2] - c[9];
                    float y0 = d0 / c[0];
                    float y1 = (d1 - c[1] * y0) / c[2];
                    float y2 = (d2 - c[3] * y0 - c[4] * y1) / c[5];
                    float maha = y0 * y0 + y1 * y1 + y2 * y2;
                    float wv = expf(-0.5f * (maha + THREE_LOG2PI) - c[6]);
                    w_ws[(size_t)b * VV + v] = wv;
                    unsigned int u = __float_as_uint(wv);
                    atomicMin(&smn[g], u);
                    atomicMax(&smx[g], u);
                }
                __syncthreads();
                if (tid < GG) {
                    segmn[b * GG + tid] = __uint_as_float(smn[tid]);
                    segmx[b * GG + tid] = __uint_as_float(smx[tid]);
                }
            }
            if (aduty) {
                if (tid < GG) {
                    int any = 0;
                    for (int bb = 0; bb < BB && !any; ++bb) {
                        for (int c = 0; c < 12; ++c) {
                            if (fabsf(contact_gaussians[((size_t)bb * GG + tid) * 12 + c]) > 1e-9f) {
                                any = 1;
                                break;
                            }
                        }
                    }
                    active_ws[tid] = any ? 1.0f : 0.0f;
                }
                if (tid == 0) { out[0] = 0.0f; out[1] = 0.0f; }
            }
            __syncthreads();
        }

        bool valid = tid < VV;
        int vc = valid ? tid : (VV - 1);
        float vx, vy, vz;
        {
            const float* vp = verts + ((size_t)b * VV + vc) * 3;
            vx = vp[0]; vy = vp[1]; vz = vp[2];
        }

        float bsv = INFINITY;
        int biv = 0;

        unsigned long long addr =
            (unsigned long long)(obj_normals + ((size_t)b * OO + (size_t)p * NPTS) * 6);
#pragma unroll 2
        for (int i = 0; i < NPTS; i += 2) {
            i4v ra, rb, rc;   // 2 rows x 24 B = 48 B = 3x s_load_dwordx4
            asm volatile(
                "s_load_dwordx4 %0, %3, 0x0\n"
                "s_load_dwordx4 %1, %3, 0x10\n"
                "s_load_dwordx4 %2, %3, 0x20\n"
                "s_waitcnt lgkmcnt(0)\n"
                : "=&s"(ra), "=&s"(rb), "=&s"(rc)
                : "s"(addr));
            {
                float dx = __int_as_float(ra.x) - vx;
                float dy = __int_as_float(ra.y) - vy;
                float dz = __int_as_float(ra.z) - vz;
                float u = fmaf(dx, dx, fmaf(dy, dy, dz * dz));
                if (u < bsv) { bsv = u; biv = i; }
            }
            {
                float dx = __int_as_float(rb.z) - vx;
                float dy = __int_as_float(rb.w) - vy;
                float dz = __int_as_float(rc.x) - vz;
                float u = fmaf(dx, dx, fmaf(dy, dy, dz * dz));
                if (u < bsv) { bsv = u; biv = i + 1; }
            }
            addr += 48;
        }
        if (valid) {
            unsigned long long key =
                ((unsigned long long)fkey(bsv) << 32) |
                (unsigned int)(p * NPTS + biv);
            pmin[(size_t)(b * P + p) * VV + tid] = key;
        }
    }
}

// ---------------- Kernel B: tree merge + weights + reduce ------------------
// grid = BB * 13 blocks of 256. tid = pi*64 + vi.
// R5: top5/pmin now hold full d^2 (not w-2dot) -> no +vv in the sqrt.
template <int LOGP>
__global__ __launch_bounds__(256) void finalize_kernel(
    const float* __restrict__ top5,
    const unsigned long long* __restrict__ pmin,
    const float* __restrict__ obj_normals,
    const float* __restrict__ verts,
    const int* __restrict__ gid,
    const float* __restrict__ w,
    const float* __restrict__ segmn,
    const float* __restrict__ segmx,
    const float* __restrict__ active,
    float* __restrict__ out) {
    constexpr int P = 1 << LOGP;
    constexpr int NM = (P + 3) / 4;
    constexpr int NCH = (VV + 63) / 64;

    __shared__ float mt[4][KNN][64];
    __shared__ unsigned long long at[4][64];
    __shared__ float rd[256], rp[256];

    int tid = threadIdx.x;
    int pi = tid >> 6;
    int vi = tid & 63;
    int b = blockIdx.x / NCH;
    int chunk = blockIdx.x - b * NCH;
    int v = chunk * 64 + vi;
    bool valid = v < VV;

    float m[KNN];
#pragma unroll
    for (int k = 0; k < KNN; ++k) m[k] = INFINITY;
    unsigned long long amin = 0xFFFFFFFFFFFFFFFFull;
    if (valid) {
#pragma unroll
        for (int r = 0; r < NM; ++r) {
            int p = pi * NM + r;
            if (p < P) {
                size_t base = ((size_t)(b * P + p) * KNN) * VV + v;
                float t[KNN];
#pragma unroll
                for (int k = 0; k < KNN; ++k) t[k] = top5[base + (size_t)k * VV];
                merge5_med3(m, t);
                unsigned long long a = pmin[(size_t)(b * P + p) * VV + v];
                if (a < amin) amin = a;
            }
        }
    }

#pragma unroll
    for (int k = 0; k < KNN; ++k) mt[pi][k][vi] = m[k];
    at[pi][vi] = amin;
    __syncthreads();

    if (pi < 2) {
        float t[KNN];
#pragma unroll
        for (int k = 0; k < KNN; ++k) t[k] = mt[pi + 2][k][vi];
        merge5_med3(m, t);
#pragma unroll
        for (int k = 0; k < KNN; ++k) mt[pi][k][vi] = m[k];
        unsigned long long a = at[pi + 2][vi];
        if (a < amin) amin = a;
        at[pi][vi] = amin;
    }
    __syncthreads();

    float cd = 0.0f, cp = 0.0f;
    if (pi == 0 && valid) {
        float t[KNN];
#pragma unroll
        for (int k = 0; k < KNN; ++k) t[k] = mt[1][k][vi];
        merge5_med3(m, t);
        unsigned long long a = at[1][vi];
        if (a < amin) amin = a;

        const float* vp = verts + ((size_t)b * VV + v) * 3;
        float vx = vp[0], vy = vp[1], vz = vp[2];

        int g = gid[v];
        float wv = w[(size_t)b * VV + v];
        float mn = segmn[b * GG + g];
        float mx = segmx[b * GG + g];
        float wn = (wv - mn) / (mx - mn);
        float eff = (active[g] != 0.0f && wn > 0.01f) ? wn : 0.0f;
        float sk = 0.0f;
#pragma unroll
        for (int k = 0; k < KNN; ++k) sk += sqrtf(fmaxf(m[k], 0.0f));
        cd = eff * sk;

        int bi = (int)(unsigned int)(amin & 0xFFFFFFFFull);
        const float* row = obj_normals + ((size_t)b * OO + bi) * 6;
        float n0 = row[3], n1 = row[4], n2 = row[5];
        float r0 = row[0] - 0.002f * n0;
        float r1 = row[1] - 0.002f * n1;
        float r2 = row[2] - 0.002f * n2;
        float dp = n0 * (vx - r0) + n1 * (vy - r1) + n2 * (vz - r2);
        cp = fmaxf(-dp, 0.0f);
    }

    rd[tid] = cd;
    rp[tid] = cp;
    __syncthreads();
    for (int s = 128; s > 0; s >>= 1) {
        if (tid < s) {
            rd[tid] += rd[tid + s];
            rp[tid] += rp[tid + s];
        }
        __syncthreads();
    }
    if (tid == 0) {
        atomicAdd(&out[0], rd[0] * (1.0f / ((float)BB * VV * KNN)));
        atomicAdd(&out[1], rp[0] * (1.0f / ((float)BB * VV)));
    }
}

template <int LOGP>
static void launch_all(const float* verts, const float* anchor_verts,
                       const float* obj_pts, const float* contact_gaussians,
                       const float* obj_normals, const float* init_verts,
                       const float* init_anchors, int* gid_ws, float* active_ws,
                       float* segmn, float* segmx, float* w_ws, float* top5,
                       unsigned long long* pmin, float* out, hipStream_t stream) {
    constexpr int P = 1 << LOGP;
    constexpr int NCH = (VV + 63) / 64;
    hipLaunchKernelGGL((scan_kernel<LOGP>), dim3(BB * 2 * P), dim3(TSCAN),
                       0, stream, verts, anchor_verts, obj_pts, contact_gaussians,
                       obj_normals, init_verts, init_anchors, gid_ws, active_ws,
                       segmn, segmx, w_ws, top5, pmin, out);
    hipLaunchKernelGGL((finalize_kernel<LOGP>), dim3(BB * NCH), dim3(256), 0, stream,
                       top5, pmin, obj_normals, verts, gid_ws, w_ws, segmn,
                       segmx, active_ws, out);
}

extern "C" void kernel_launch(void* const* d_in, const int* in_sizes, int n_in,
                              void* d_out, int out_size, void* d_ws, size_t ws_size,
                              hipStream_t stream) {
    const float* verts = (const float*)d_in[0];
    const float* anchor_verts = (const float*)d_in[1];
    const float* obj_pts = (const float*)d_in[2];
    const float* contact_gaussians = (const float*)d_in[3];
    const float* obj_normals = (const float*)d_in[4];
    const float* init_verts = (const float*)d_in[5];
    const float* init_anchors = (const float*)d_in[6];
    float* out = (float*)d_out;

    char* ws = (char*)d_ws;
    int* gid_ws = (int*)(ws + 0);                       // 778 i  -> 4096
    float* active_ws = (float*)(ws + 4096);             // 32 f   -> 4224
    float* segmn = (float*)(ws + 4224);                 // 512 f  -> 6272
    float* segmx = (float*)(ws + 6272);                 // 512 f  -> 8320
    float* w_ws = (float*)(ws + 8320);                  // 12448 f-> 58112 (pad 58368)
    const size_t base = 58368;

    // P=16 (R1's P=32 regressed: occupancy unchanged, doubled writes).
    int logP = 4;
    while (logP > 0) {
        size_t need = base + (size_t)BB * (1 << logP) * VV * (KNN * 4 + 8);
        if (need <= ws_size) break;
        --logP;
    }

    unsigned long long* pmin = (unsigned long long*)(ws + base);
    float* top5 = (float*)(ws + base + (size_t)BB * ((size_t)1 << logP) * VV * 8);

#define LAUNCH(L)                                                              \
    launch_all<L>(verts, anchor_verts, obj_pts, contact_gaussians,             \
                  obj_normals, init_verts, init_anchors, gid_ws, active_ws,    \
                  segmn, segmx, w_ws, top5, pmin, out, stream)
    switch (logP) {
        case 4: LAUNCH(4); break;
        case 3: LAUNCH(3); break;
        case 2: LAUNCH(2); break;
        case 1: LAUNCH(1); break;
        default: LAUNCH(0); break;
    }
#undef LAUNCH
}

// Round 7
// 157.016 us; speedup vs baseline: 1.2150x; 1.2150x over previous
//
#include <hip/hip_runtime.h>
#include <math.h>

#define BB 16
#define VV 778
#define OO 8192
#define GG 32
#define KNN 5
#define THREE_LOG2PI 5.513631199228036f
#define TSCAN 832   // 13 waves x 1 slot (R2's best-measured shape)

#define MED3 __builtin_amdgcn_fmed3f

// sorted ascending insert: t[j] = min(t[j], max(t[j-1], s)) == med3(s, t[j-1], t[j])
__device__ __forceinline__ void insert5_med3(float (&t)[KNN], float s) {
    t[4] = MED3(s, t[3], t[4]);
    t[3] = MED3(s, t[2], t[3]);
    t[2] = MED3(s, t[1], t[2]);
    t[1] = MED3(s, t[0], t[1]);
    t[0] = fminf(t[0], s);
}

// merge sorted ascending b[5] into sorted ascending m[5]: 15 ops
__device__ __forceinline__ void merge5_med3(float (&m)[KNN], const float (&b)[KNN]) {
    m[4] = MED3(b[0], m[3], m[4]);
    m[3] = MED3(b[0], m[2], m[3]);
    m[2] = MED3(b[0], m[1], m[2]);
    m[1] = MED3(b[0], m[0], m[1]);
    m[0] = fminf(m[0], b[0]);
    m[4] = MED3(b[1], m[3], m[4]);
    m[3] = MED3(b[1], m[2], m[3]);
    m[2] = MED3(b[1], m[1], m[2]);
    m[1] = fminf(m[1], b[1]);
    m[4] = MED3(b[2], m[3], m[4]);
    m[3] = MED3(b[2], m[2], m[3]);
    m[2] = fminf(m[2], b[2]);
    m[4] = MED3(b[3], m[3], m[4]);
    m[3] = fminf(m[3], b[3]);
    m[4] = fminf(m[4], b[4]);
}

// monotone float->uint key: a<b <=> fkey(a)<fkey(b)
__device__ __forceinline__ unsigned int fkey(float s) {
    unsigned int u = __float_as_uint(s);
    unsigned int m = (u & 0x80000000u) ? 0xFFFFFFFFu : 0x80000000u;
    return u ^ m;
}

// broadcast lane j's float to all lanes via v_readlane (VALU pipe -> SGPR)
__device__ __forceinline__ float bcast_lane(float v, int j) {
    return __uint_as_float(
        (unsigned int)__builtin_amdgcn_readlane((int)__float_as_uint(v), j));
}

// ---------------- Kernel A: two block families, 832 thr x 1 vertex slot ----
// R6: fam-1 = exact R2 (LDS b128 broadcast; best measured 52.4us scan).
// fam-2 moved OFF the LDS pipe: lane-load 64-row windows of the normals
// partition, then v_readlane-broadcast (VALU->SGPR, no LDS, no barriers,
// no waitcnt - unlike R5's serialized SMEM). d2 computed directly; pmin
// only carries the argmin INDEX (value unused in finalize), ordering is
// consistent per vertex -> exact argmin preserved (R5 validated d2 form).
template <int LOGP>
__global__ __launch_bounds__(TSCAN) void scan_kernel(
    const float* __restrict__ verts,
    const float* __restrict__ anchor_verts,
    const float* __restrict__ obj_pts,
    const float* __restrict__ contact_gaussians,
    const float* __restrict__ obj_normals,
    const float* __restrict__ init_verts,
    const float* __restrict__ init_anchors,
    int* __restrict__ gid_ws,
    float* __restrict__ active_ws,
    float* __restrict__ segmn,
    float* __restrict__ segmx,
    float* __restrict__ w_ws,
    float* __restrict__ top5,                 // [B][P][KNN][VV]
    unsigned long long* __restrict__ pmin,    // [B][P][VV] (fkey<<32)|idx
    float* __restrict__ out) {
    constexpr int P = 1 << LOGP;
    constexpr int NPTS = OO >> LOGP;
    constexpr int CH = (NPTS < 512) ? NPTS : 512;

    __shared__ float4 tile[CH];
    __shared__ float anc[GG * 4];
    __shared__ float cholb[GG * 10];
    __shared__ unsigned short gidl[VV];
    __shared__ unsigned int smn[GG], smx[GG];

    int tid = threadIdx.x;
    int bid = blockIdx.x;

    if (bid < BB * P) {
        // ================= Family 1: KNN top-5 (exact R2) ==================
        int p = bid & (P - 1);
        int b = bid >> LOGP;

        bool valid = tid < VV;
        int vc = valid ? tid : (VV - 1);
        float X, Y, Z;
        {
            const float* vp = verts + ((size_t)b * VV + vc) * 3;
            X = -2.0f * vp[0];
            Y = -2.0f * vp[1];
            Z = -2.0f * vp[2];
        }

        float t[KNN];
#pragma unroll
        for (int k = 0; k < KNN; ++k) t[k] = INFINITY;

        const float* pb = obj_pts + ((size_t)b * OO + p * NPTS) * 3;
        for (int c0 = 0; c0 < NPTS; c0 += CH) {
            if (c0 != 0) __syncthreads();   // block-uniform; multi-chunk only
            for (int j = tid; j < CH; j += TSCAN) {
                const float* q = pb + (size_t)(c0 + j) * 3;
                float a0 = q[0], a1 = q[1], a2 = q[2];
                tile[j] = make_float4(a0, a1, a2, a0 * a0 + a1 * a1 + a2 * a2);
            }
            __syncthreads();
#pragma unroll 8
            for (int i = 0; i < CH; ++i) {
                float4 q = tile[i];
                float sv = fmaf(X, q.x, fmaf(Y, q.y, fmaf(Z, q.z, q.w)));
                insert5_med3(t, sv);
            }
        }
        if (valid) {
            size_t base = ((size_t)(b * P + p) * KNN) * VV + tid;
#pragma unroll
            for (int k = 0; k < KNN; ++k)
                top5[base + (size_t)k * VV] = t[k];
        }
        return;
    }

    // ================= Family 2: NN argmin (+ duties), readlane path =======
    {
        int sub = bid - BB * P;
        int p = sub & (P - 1);
        int b = sub >> LOGP;

        bool wduty = (p == 0);                    // 16 blocks, one per b
        bool aduty = (p == 1 && b == 0);          // 1 block
        if (wduty || aduty) {
            if (tid < GG) {
                float x = init_anchors[tid * 3 + 0];
                float y = init_anchors[tid * 3 + 1];
                float z = init_anchors[tid * 3 + 2];
                anc[tid * 4 + 0] = x; anc[tid * 4 + 1] = y;
                anc[tid * 4 + 2] = z; anc[tid * 4 + 3] = x * x + y * y + z * z;
                smn[tid] = 0x7F800000u;
                smx[tid] = 0u;
                if (wduty) {
                    const float* cg2 = contact_gaussians + ((size_t)b * GG + tid) * 12;
                    const float* av = anchor_verts + ((size_t)b * GG + tid) * 3;
                    float c00 = cg2[3];
                    float c10 = cg2[6], c11 = cg2[7];
                    float c20 = cg2[9], c21 = cg2[10], c22 = cg2[11];
                    float L00 = sqrtf(c00);
                    float L10 = c10 / L00;
                    float L20 = c20 / L00;
                    float L11 = sqrtf(c11 - L10 * L10);
                    float L21 = (c21 - L20 * L10) / L11;
                    float L22 = sqrtf(c22 - L20 * L20 - L21 * L21);
                    float* c = cholb + tid * 10;
                    c[0] = L00; c[1] = L10; c[2] = L11;
                    c[3] = L20; c[4] = L21; c[5] = L22;
                    c[6] = logf(L00) + logf(L11) + logf(L22);
                    c[7] = cg2[0] + av[0];
                    c[8] = cg2[1] + av[1];
                    c[9] = cg2[2] + av[2];
                }
            }
            __syncthreads();
            for (int v = tid; v < VV; v += TSCAN) {
                float x = init_verts[v * 3 + 0];
                float y = init_verts[v * 3 + 1];
                float z = init_verts[v * 3 + 2];
                float vv = x * x + y * y + z * z;
                float best = INFINITY;
                int bg = 0;
                for (int g = 0; g < GG; ++g) {
                    float d2 = vv + anc[g * 4 + 3] -
                               2.0f * (x * anc[g * 4 + 0] + y * anc[g * 4 + 1] + z * anc[g * 4 + 2]);
                    d2 = fmaxf(d2, 0.0f);
                    if (d2 < best) { best = d2; bg = g; }
                }
                gidl[v] = (unsigned short)bg;
                if (aduty) gid_ws[v] = bg;
            }
            __syncthreads();
            if (wduty) {
                for (int v = tid; v < VV; v += TSCAN) {
                    int g = gidl[v];
                    const float* c = cholb + g * 10;
                    const float* vp = verts + ((size_t)b * VV + v) * 3;
                    float d0 = vp[0] - c[7];
                    float d1 = vp[1] - c[8];
                    float d2 = vp[2] - c[9];
                    float y0 = d0 / c[0];
                    float y1 = (d1 - c[1] * y0) / c[2];
                    float y2 = (d2 - c[3] * y0 - c[4] * y1) / c[5];
                    float maha = y0 * y0 + y1 * y1 + y2 * y2;
                    float wv = expf(-0.5f * (maha + THREE_LOG2PI) - c[6]);
                    w_ws[(size_t)b * VV + v] = wv;
                    unsigned int u = __float_as_uint(wv);
                    atomicMin(&smn[g], u);
                    atomicMax(&smx[g], u);
                }
                __syncthreads();
                if (tid < GG) {
                    segmn[b * GG + tid] = __uint_as_float(smn[tid]);
                    segmx[b * GG + tid] = __uint_as_float(smx[tid]);
                }
            }
            if (aduty) {
                if (tid < GG) {
                    int any = 0;
                    for (int bb = 0; bb < BB && !any; ++bb) {
                        for (int c = 0; c < 12; ++c) {
                            if (fabsf(contact_gaussians[((size_t)bb * GG + tid) * 12 + c]) > 1e-9f) {
                                any = 1;
                                break;
                            }
                        }
                    }
                    active_ws[tid] = any ? 1.0f : 0.0f;
                }
                if (tid == 0) { out[0] = 0.0f; out[1] = 0.0f; }
            }
            __syncthreads();
        }

        bool valid = tid < VV;
        int vc = valid ? tid : (VV - 1);
        float vx, vy, vz;
        {
            const float* vp = verts + ((size_t)b * VV + vc) * 3;
            vx = vp[0]; vy = vp[1]; vz = vp[2];
        }

        float bsv = INFINITY;
        int biv = 0;
        int lane = tid & 63;

        const float* nbp = obj_normals + ((size_t)b * OO + p * NPTS) * 6;
        for (int r = 0; r < NPTS; r += 64) {
            // each lane loads one row of the 64-row window (L1-cached
            // across the block's 13 waves; 3 x 4B strided by 24B)
            const float* row = nbp + (size_t)(r + lane) * 6;
            float qx = row[0], qy = row[1], qz = row[2];
#pragma unroll 16
            for (int j = 0; j < 64; ++j) {
                float px = bcast_lane(qx, j);
                float py = bcast_lane(qy, j);
                float pz = bcast_lane(qz, j);
                float dx = px - vx, dy = py - vy, dz = pz - vz;
                float u = fmaf(dx, dx, fmaf(dy, dy, dz * dz));
                int gi = r + j;
                if (u < bsv) { bsv = u; biv = gi; }
            }
        }
        if (valid) {
            unsigned long long key =
                ((unsigned long long)fkey(bsv) << 32) |
                (unsigned int)(p * NPTS + biv);
            pmin[(size_t)(b * P + p) * VV + tid] = key;
        }
    }
}

// ---------------- Kernel B: tree merge + weights + reduce ------------------
// grid = BB * 13 blocks of 256. tid = pi*64 + vi.  (exact R2; top5 stores
// w-2dot so +vv stays; pmin value is discarded, only index used.)
template <int LOGP>
__global__ __launch_bounds__(256) void finalize_kernel(
    const float* __restrict__ top5,
    const unsigned long long* __restrict__ pmin,
    const float* __restrict__ obj_normals,
    const float* __restrict__ verts,
    const int* __restrict__ gid,
    const float* __restrict__ w,
    const float* __restrict__ segmn,
    const float* __restrict__ segmx,
    const float* __restrict__ active,
    float* __restrict__ out) {
    constexpr int P = 1 << LOGP;
    constexpr int NM = (P + 3) / 4;
    constexpr int NCH = (VV + 63) / 64;

    __shared__ float mt[4][KNN][64];
    __shared__ unsigned long long at[4][64];
    __shared__ float rd[256], rp[256];

    int tid = threadIdx.x;
    int pi = tid >> 6;
    int vi = tid & 63;
    int b = blockIdx.x / NCH;
    int chunk = blockIdx.x - b * NCH;
    int v = chunk * 64 + vi;
    bool valid = v < VV;

    float m[KNN];
#pragma unroll
    for (int k = 0; k < KNN; ++k) m[k] = INFINITY;
    unsigned long long amin = 0xFFFFFFFFFFFFFFFFull;
    if (valid) {
#pragma unroll
        for (int r = 0; r < NM; ++r) {
            int p = pi * NM + r;
            if (p < P) {
                size_t base = ((size_t)(b * P + p) * KNN) * VV + v;
                float t[KNN];
#pragma unroll
                for (int k = 0; k < KNN; ++k) t[k] = top5[base + (size_t)k * VV];
                merge5_med3(m, t);
                unsigned long long a = pmin[(size_t)(b * P + p) * VV + v];
                if (a < amin) amin = a;
            }
        }
    }

#pragma unroll
    for (int k = 0; k < KNN; ++k) mt[pi][k][vi] = m[k];
    at[pi][vi] = amin;
    __syncthreads();

    if (pi < 2) {
        float t[KNN];
#pragma unroll
        for (int k = 0; k < KNN; ++k) t[k] = mt[pi + 2][k][vi];
        merge5_med3(m, t);
#pragma unroll
        for (int k = 0; k < KNN; ++k) mt[pi][k][vi] = m[k];
        unsigned long long a = at[pi + 2][vi];
        if (a < amin) amin = a;
        at[pi][vi] = amin;
    }
    __syncthreads();

    float cd = 0.0f, cp = 0.0f;
    if (pi == 0 && valid) {
        float t[KNN];
#pragma unroll
        for (int k = 0; k < KNN; ++k) t[k] = mt[1][k][vi];
        merge5_med3(m, t);
        unsigned long long a = at[1][vi];
        if (a < amin) amin = a;

        const float* vp = verts + ((size_t)b * VV + v) * 3;
        float vx = vp[0], vy = vp[1], vz = vp[2];
        float vv = vx * vx + vy * vy + vz * vz;

        int g = gid[v];
        float wv = w[(size_t)b * VV + v];
        float mn = segmn[b * GG + g];
        float mx = segmx[b * GG + g];
        float wn = (wv - mn) / (mx - mn);
        float eff = (active[g] != 0.0f && wn > 0.01f) ? wn : 0.0f;
        float sk = 0.0f;
#pragma unroll
        for (int k = 0; k < KNN; ++k) sk += sqrtf(fmaxf(vv + m[k], 0.0f));
        cd = eff * sk;

        int bi = (int)(unsigned int)(amin & 0xFFFFFFFFull);
        const float* row = obj_normals + ((size_t)b * OO + bi) * 6;
        float n0 = row[3], n1 = row[4], n2 = row[5];
        float r0 = row[0] - 0.002f * n0;
        float r1 = row[1] - 0.002f * n1;
        float r2 = row[2] - 0.002f * n2;
        float dp = n0 * (vx - r0) + n1 * (vy - r1) + n2 * (vz - r2);
        cp = fmaxf(-dp, 0.0f);
    }

    rd[tid] = cd;
    rp[tid] = cp;
    __syncthreads();
    for (int s = 128; s > 0; s >>= 1) {
        if (tid < s) {
            rd[tid] += rd[tid + s];
            rp[tid] += rp[tid + s];
        }
        __syncthreads();
    }
    if (tid == 0) {
        atomicAdd(&out[0], rd[0] * (1.0f / ((float)BB * VV * KNN)));
        atomicAdd(&out[1], rp[0] * (1.0f / ((float)BB * VV)));
    }
}

template <int LOGP>
static void launch_all(const float* verts, const float* anchor_verts,
                       const float* obj_pts, const float* contact_gaussians,
                       const float* obj_normals, const float* init_verts,
                       const float* init_anchors, int* gid_ws, float* active_ws,
                       float* segmn, float* segmx, float* w_ws, float* top5,
                       unsigned long long* pmin, float* out, hipStream_t stream) {
    constexpr int P = 1 << LOGP;
    constexpr int NCH = (VV + 63) / 64;
    hipLaunchKernelGGL((scan_kernel<LOGP>), dim3(BB * 2 * P), dim3(TSCAN),
                       0, stream, verts, anchor_verts, obj_pts, contact_gaussians,
                       obj_normals, init_verts, init_anchors, gid_ws, active_ws,
                       segmn, segmx, w_ws, top5, pmin, out);
    hipLaunchKernelGGL((finalize_kernel<LOGP>), dim3(BB * NCH), dim3(256), 0, stream,
                       top5, pmin, obj_normals, verts, gid_ws, w_ws, segmn,
                       segmx, active_ws, out);
}

extern "C" void kernel_launch(void* const* d_in, const int* in_sizes, int n_in,
                              void* d_out, int out_size, void* d_ws, size_t ws_size,
                              hipStream_t stream) {
    const float* verts = (const float*)d_in[0];
    const float* anchor_verts = (const float*)d_in[1];
    const float* obj_pts = (const float*)d_in[2];
    const float* contact_gaussians = (const float*)d_in[3];
    const float* obj_normals = (const float*)d_in[4];
    const float* init_verts = (const float*)d_in[5];
    const float* init_anchors = (const float*)d_in[6];
    float* out = (float*)d_out;

    char* ws = (char*)d_ws;
    int* gid_ws = (int*)(ws + 0);                       // 778 i  -> 4096
    float* active_ws = (float*)(ws + 4096);             // 32 f   -> 4224
    float* segmn = (float*)(ws + 4224);                 // 512 f  -> 6272
    float* segmx = (float*)(ws + 6272);                 // 512 f  -> 8320
    float* w_ws = (float*)(ws + 8320);                  // 12448 f-> 58112 (pad 58368)
    const size_t base = 58368;

    // P=16 (R1's P=32 regressed: occupancy unchanged, doubled writes).
    int logP = 4;
    while (logP > 0) {
        size_t need = base + (size_t)BB * (1 << logP) * VV * (KNN * 4 + 8);
        if (need <= ws_size) break;
        --logP;
    }

    unsigned long long* pmin = (unsigned long long*)(ws + base);
    float* top5 = (float*)(ws + base + (size_t)BB * ((size_t)1 << logP) * VV * 8);

#define LAUNCH(L)                                                              \
    launch_all<L>(verts, anchor_verts, obj_pts, contact_gaussians,             \
                  obj_normals, init_verts, init_anchors, gid_ws, active_ws,    \
                  segmn, segmx, w_ws, top5, pmin, out, stream)
    switch (logP) {
        case 4: LAUNCH(4); break;
        case 3: LAUNCH(3); break;
        case 2: LAUNCH(2); break;
        case 1: LAUNCH(1); break;
        default: LAUNCH(0); break;
    }
#undef LAUNCH
}

// Round 8
// 132.450 us; speedup vs baseline: 1.4404x; 1.1855x over previous
//
#include <hip/hip_runtime.h>
#include <math.h>

#define BB 16
#define VV 778
#define OO 8192
#define GG 32
#define KNN 5
#define THREE_LOG2PI 5.513631199228036f
#define TSCAN 832   // 13 waves x 1 slot (R2's best-measured shape)

#define MED3 __builtin_amdgcn_fmed3f

// sorted ascending insert: t[j] = min(t[j], max(t[j-1], s)) == med3(s, t[j-1], t[j])
__device__ __forceinline__ void insert5_med3(float (&t)[KNN], float s) {
    t[4] = MED3(s, t[3], t[4]);
    t[3] = MED3(s, t[2], t[3]);
    t[2] = MED3(s, t[1], t[2]);
    t[1] = MED3(s, t[0], t[1]);
    t[0] = fminf(t[0], s);
}

// merge sorted ascending b[5] into sorted ascending m[5]: 15 ops
__device__ __forceinline__ void merge5_med3(float (&m)[KNN], const float (&b)[KNN]) {
    m[4] = MED3(b[0], m[3], m[4]);
    m[3] = MED3(b[0], m[2], m[3]);
    m[2] = MED3(b[0], m[1], m[2]);
    m[1] = MED3(b[0], m[0], m[1]);
    m[0] = fminf(m[0], b[0]);
    m[4] = MED3(b[1], m[3], m[4]);
    m[3] = MED3(b[1], m[2], m[3]);
    m[2] = MED3(b[1], m[1], m[2]);
    m[1] = fminf(m[1], b[1]);
    m[4] = MED3(b[2], m[3], m[4]);
    m[3] = MED3(b[2], m[2], m[3]);
    m[2] = fminf(m[2], b[2]);
    m[4] = MED3(b[3], m[3], m[4]);
    m[3] = fminf(m[3], b[3]);
    m[4] = fminf(m[4], b[4]);
}

// monotone float->uint key: a<b <=> fkey(a)<fkey(b)
__device__ __forceinline__ unsigned int fkey(float s) {
    unsigned int u = __float_as_uint(s);
    unsigned int m = (u & 0x80000000u) ? 0xFFFFFFFFu : 0x80000000u;
    return u ^ m;
}

// ---------------- Kernel A: fam1 / fam2 / duty blocks ----------------------
// R7: R2 structure + per-wave loop ROTATION to break the barrier convoy
// (R2 measured = VALU 21us + LDS 22us SERIAL; all 13 waves left the staging
// barrier in lockstep -> LDS-burst phase and VALU phase alternate instead of
// overlapping). Each wave starts its point loop at offset ((2w+blkpar)*20),
// as two linear sub-loops (keeps ds_read immediate-offset folding).
// Legality: top-5 via med3 network is ORDER-INVARIANT (exact multiset of 5
// smallest). fam2 argmin made order-invariant via packed u64 (d2bits<<32|idx)
// min (d2 >= 0 -> raw bits monotone); duty work moved to 17 dedicated tail
// blocks so scan blocks are uniform.
template <int LOGP>
__global__ __launch_bounds__(TSCAN) void scan_kernel(
    const float* __restrict__ verts,
    const float* __restrict__ anchor_verts,
    const float* __restrict__ obj_pts,
    const float* __restrict__ contact_gaussians,
    const float* __restrict__ obj_normals,
    const float* __restrict__ init_verts,
    const float* __restrict__ init_anchors,
    int* __restrict__ gid_ws,
    float* __restrict__ active_ws,
    float* __restrict__ segmn,
    float* __restrict__ segmx,
    float* __restrict__ w_ws,
    float* __restrict__ top5,                 // [B][P][KNN][VV]
    unsigned long long* __restrict__ pmin,    // [B][P][VV] (fkey<<32)|idx
    float* __restrict__ out) {
    constexpr int P = 1 << LOGP;
    constexpr int NPTS = OO >> LOGP;
    constexpr int CH = (NPTS < 512) ? NPTS : 512;

    __shared__ float4 tile[CH];
    __shared__ float anc[GG * 4];
    __shared__ float cholb[GG * 10];
    __shared__ unsigned short gidl[VV];
    __shared__ unsigned int smn[GG], smx[GG];

    int tid = threadIdx.x;
    int bid = blockIdx.x;
    int woff = ((((tid >> 6) << 1) | (bid & 1)) * 20) & (CH - 1);

    if (bid < BB * P) {
        // ================= Family 1: KNN top-5 (R2 + rotation) =============
        int p = bid & (P - 1);
        int b = bid >> LOGP;

        bool valid = tid < VV;
        int vc = valid ? tid : (VV - 1);
        float X, Y, Z;
        {
            const float* vp = verts + ((size_t)b * VV + vc) * 3;
            X = -2.0f * vp[0];
            Y = -2.0f * vp[1];
            Z = -2.0f * vp[2];
        }

        float t[KNN];
#pragma unroll
        for (int k = 0; k < KNN; ++k) t[k] = INFINITY;

        const float* pb = obj_pts + ((size_t)b * OO + p * NPTS) * 3;
        for (int c0 = 0; c0 < NPTS; c0 += CH) {
            if (c0 != 0) __syncthreads();   // block-uniform; multi-chunk only
            for (int j = tid; j < CH; j += TSCAN) {
                const float* q = pb + (size_t)(c0 + j) * 3;
                float a0 = q[0], a1 = q[1], a2 = q[2];
                tile[j] = make_float4(a0, a1, a2, a0 * a0 + a1 * a1 + a2 * a2);
            }
            __syncthreads();
#pragma unroll 8
            for (int i = woff; i < CH; ++i) {
                float4 q = tile[i];
                float sv = fmaf(X, q.x, fmaf(Y, q.y, fmaf(Z, q.z, q.w)));
                insert5_med3(t, sv);
            }
#pragma unroll 8
            for (int i = 0; i < woff; ++i) {
                float4 q = tile[i];
                float sv = fmaf(X, q.x, fmaf(Y, q.y, fmaf(Z, q.z, q.w)));
                insert5_med3(t, sv);
            }
        }
        if (valid) {
            size_t base = ((size_t)(b * P + p) * KNN) * VV + tid;
#pragma unroll
            for (int k = 0; k < KNN; ++k)
                top5[base + (size_t)k * VV] = t[k];
        }
        return;
    }

    if (bid < 2 * BB * P) {
        // ================= Family 2: NN argmin (rotation, packed u64) ======
        int sub = bid - BB * P;
        int p = sub & (P - 1);
        int b = sub >> LOGP;

        bool valid = tid < VV;
        int vc = valid ? tid : (VV - 1);
        float vx, vy, vz;
        {
            const float* vp = verts + ((size_t)b * VV + vc) * 3;
            vx = vp[0]; vy = vp[1]; vz = vp[2];
        }

        unsigned long long kmin = 0xFFFFFFFFFFFFFFFFull;

        const float* nbp = obj_normals + ((size_t)b * OO + p * NPTS) * 6;
        for (int c0 = 0; c0 < NPTS; c0 += CH) {
            if (c0 != 0) __syncthreads();
            for (int j = tid; j < CH; j += TSCAN) {
                const float* r = nbp + (size_t)(c0 + j) * 6;
                float b0 = r[0], b1 = r[1], b2 = r[2];
                tile[j] = make_float4(b0, b1, b2, 0.0f);
            }
            __syncthreads();
#pragma unroll 8
            for (int i = woff; i < CH; ++i) {
                float4 q = tile[i];
                float dx = q.x - vx, dy = q.y - vy, dz = q.z - vz;
                float u = fmaf(dx, dx, fmaf(dy, dy, dz * dz));   // d^2 >= 0
                unsigned long long key =
                    ((unsigned long long)__float_as_uint(u) << 32) |
                    (unsigned int)(c0 + i);
                if (key < kmin) kmin = key;
            }
#pragma unroll 8
            for (int i = 0; i < woff; ++i) {
                float4 q = tile[i];
                float dx = q.x - vx, dy = q.y - vy, dz = q.z - vz;
                float u = fmaf(dx, dx, fmaf(dy, dy, dz * dz));
                unsigned long long key =
                    ((unsigned long long)__float_as_uint(u) << 32) |
                    (unsigned int)(c0 + i);
                if (key < kmin) kmin = key;
            }
        }
        if (valid) {
            unsigned int ub = (unsigned int)(kmin >> 32);   // d^2 bits (>=0)
            unsigned int gi = (unsigned int)kmin + (unsigned int)(p * NPTS);
            pmin[(size_t)(b * P + p) * VV + tid] =
                ((unsigned long long)(ub | 0x80000000u) << 32) | gi;  // fkey(+)
        }
        return;
    }

    // ================= Duty blocks: 16 wduty + 1 aduty =====================
    {
        int d = bid - 2 * BB * P;
        if (d < BB) {
            int b = d;
            if (tid < GG) {
                float x = init_anchors[tid * 3 + 0];
                float y = init_anchors[tid * 3 + 1];
                float z = init_anchors[tid * 3 + 2];
                anc[tid * 4 + 0] = x; anc[tid * 4 + 1] = y;
                anc[tid * 4 + 2] = z; anc[tid * 4 + 3] = x * x + y * y + z * z;
                smn[tid] = 0x7F800000u;
                smx[tid] = 0u;
                const float* cg2 = contact_gaussians + ((size_t)b * GG + tid) * 12;
                const float* av = anchor_verts + ((size_t)b * GG + tid) * 3;
                float c00 = cg2[3];
                float c10 = cg2[6], c11 = cg2[7];
                float c20 = cg2[9], c21 = cg2[10], c22 = cg2[11];
                float L00 = sqrtf(c00);
                float L10 = c10 / L00;
                float L20 = c20 / L00;
                float L11 = sqrtf(c11 - L10 * L10);
                float L21 = (c21 - L20 * L10) / L11;
                float L22 = sqrtf(c22 - L20 * L20 - L21 * L21);
                float* c = cholb + tid * 10;
                c[0] = L00; c[1] = L10; c[2] = L11;
                c[3] = L20; c[4] = L21; c[5] = L22;
                c[6] = logf(L00) + logf(L11) + logf(L22);
                c[7] = cg2[0] + av[0];
                c[8] = cg2[1] + av[1];
                c[9] = cg2[2] + av[2];
            }
            __syncthreads();
            for (int v = tid; v < VV; v += TSCAN) {
                float x = init_verts[v * 3 + 0];
                float y = init_verts[v * 3 + 1];
                float z = init_verts[v * 3 + 2];
                float vv = x * x + y * y + z * z;
                float best = INFINITY;
                int bg = 0;
                for (int g = 0; g < GG; ++g) {
                    float d2 = vv + anc[g * 4 + 3] -
                               2.0f * (x * anc[g * 4 + 0] + y * anc[g * 4 + 1] + z * anc[g * 4 + 2]);
                    d2 = fmaxf(d2, 0.0f);
                    if (d2 < best) { best = d2; bg = g; }
                }
                gidl[v] = (unsigned short)bg;
            }
            __syncthreads();
            for (int v = tid; v < VV; v += TSCAN) {
                int g = gidl[v];
                const float* c = cholb + g * 10;
                const float* vp = verts + ((size_t)b * VV + v) * 3;
                float d0 = vp[0] - c[7];
                float d1 = vp[1] - c[8];
                float d2 = vp[2] - c[9];
                float y0 = d0 / c[0];
                float y1 = (d1 - c[1] * y0) / c[2];
                float y2 = (d2 - c[3] * y0 - c[4] * y1) / c[5];
                float maha = y0 * y0 + y1 * y1 + y2 * y2;
                float wv = expf(-0.5f * (maha + THREE_LOG2PI) - c[6]);
                w_ws[(size_t)b * VV + v] = wv;
                unsigned int u = __float_as_uint(wv);
                atomicMin(&smn[g], u);
                atomicMax(&smx[g], u);
            }
            __syncthreads();
            if (tid < GG) {
                segmn[b * GG + tid] = __uint_as_float(smn[tid]);
                segmx[b * GG + tid] = __uint_as_float(smx[tid]);
            }
        } else {
            // aduty
            if (tid < GG) {
                float x = init_anchors[tid * 3 + 0];
                float y = init_anchors[tid * 3 + 1];
                float z = init_anchors[tid * 3 + 2];
                anc[tid * 4 + 0] = x; anc[tid * 4 + 1] = y;
                anc[tid * 4 + 2] = z; anc[tid * 4 + 3] = x * x + y * y + z * z;
            }
            __syncthreads();
            for (int v = tid; v < VV; v += TSCAN) {
                float x = init_verts[v * 3 + 0];
                float y = init_verts[v * 3 + 1];
                float z = init_verts[v * 3 + 2];
                float vv = x * x + y * y + z * z;
                float best = INFINITY;
                int bg = 0;
                for (int g = 0; g < GG; ++g) {
                    float d2 = vv + anc[g * 4 + 3] -
                               2.0f * (x * anc[g * 4 + 0] + y * anc[g * 4 + 1] + z * anc[g * 4 + 2]);
                    d2 = fmaxf(d2, 0.0f);
                    if (d2 < best) { best = d2; bg = g; }
                }
                gid_ws[v] = bg;
            }
            if (tid < GG) {
                int any = 0;
                for (int bb = 0; bb < BB && !any; ++bb) {
                    for (int c = 0; c < 12; ++c) {
                        if (fabsf(contact_gaussians[((size_t)bb * GG + tid) * 12 + c]) > 1e-9f) {
                            any = 1;
                            break;
                        }
                    }
                }
                active_ws[tid] = any ? 1.0f : 0.0f;
            }
            if (tid == 0) { out[0] = 0.0f; out[1] = 0.0f; }
        }
    }
}

// ---------------- Kernel B: tree merge + weights + reduce ------------------
// grid = BB * 13 blocks of 256. tid = pi*64 + vi.  (top5 stores w-2dot so
// +vv stays; pmin value is discarded, only index used.)
template <int LOGP>
__global__ __launch_bounds__(256) void finalize_kernel(
    const float* __restrict__ top5,
    const unsigned long long* __restrict__ pmin,
    const float* __restrict__ obj_normals,
    const float* __restrict__ verts,
    const int* __restrict__ gid,
    const float* __restrict__ w,
    const float* __restrict__ segmn,
    const float* __restrict__ segmx,
    const float* __restrict__ active,
    float* __restrict__ out) {
    constexpr int P = 1 << LOGP;
    constexpr int NM = (P + 3) / 4;
    constexpr int NCH = (VV + 63) / 64;

    __shared__ float mt[4][KNN][64];
    __shared__ unsigned long long at[4][64];
    __shared__ float rd[256], rp[256];

    int tid = threadIdx.x;
    int pi = tid >> 6;
    int vi = tid & 63;
    int b = blockIdx.x / NCH;
    int chunk = blockIdx.x - b * NCH;
    int v = chunk * 64 + vi;
    bool valid = v < VV;

    float m[KNN];
#pragma unroll
    for (int k = 0; k < KNN; ++k) m[k] = INFINITY;
    unsigned long long amin = 0xFFFFFFFFFFFFFFFFull;
    if (valid) {
#pragma unroll
        for (int r = 0; r < NM; ++r) {
            int p = pi * NM + r;
            if (p < P) {
                size_t base = ((size_t)(b * P + p) * KNN) * VV + v;
                float t[KNN];
#pragma unroll
                for (int k = 0; k < KNN; ++k) t[k] = top5[base + (size_t)k * VV];
                merge5_med3(m, t);
                unsigned long long a = pmin[(size_t)(b * P + p) * VV + v];
                if (a < amin) amin = a;
            }
        }
    }

#pragma unroll
    for (int k = 0; k < KNN; ++k) mt[pi][k][vi] = m[k];
    at[pi][vi] = amin;
    __syncthreads();

    if (pi < 2) {
        float t[KNN];
#pragma unroll
        for (int k = 0; k < KNN; ++k) t[k] = mt[pi + 2][k][vi];
        merge5_med3(m, t);
#pragma unroll
        for (int k = 0; k < KNN; ++k) mt[pi][k][vi] = m[k];
        unsigned long long a = at[pi + 2][vi];
        if (a < amin) amin = a;
        at[pi][vi] = amin;
    }
    __syncthreads();

    float cd = 0.0f, cp = 0.0f;
    if (pi == 0 && valid) {
        float t[KNN];
#pragma unroll
        for (int k = 0; k < KNN; ++k) t[k] = mt[1][k][vi];
        merge5_med3(m, t);
        unsigned long long a = at[1][vi];
        if (a < amin) amin = a;

        const float* vp = verts + ((size_t)b * VV + v) * 3;
        float vx = vp[0], vy = vp[1], vz = vp[2];
        float vv = vx * vx + vy * vy + vz * vz;

        int g = gid[v];
        float wv = w[(size_t)b * VV + v];
        float mn = segmn[b * GG + g];
        float mx = segmx[b * GG + g];
        float wn = (wv - mn) / (mx - mn);
        float eff = (active[g] != 0.0f && wn > 0.01f) ? wn : 0.0f;
        float sk = 0.0f;
#pragma unroll
        for (int k = 0; k < KNN; ++k) sk += sqrtf(fmaxf(vv + m[k], 0.0f));
        cd = eff * sk;

        int bi = (int)(unsigned int)(amin & 0xFFFFFFFFull);
        const float* row = obj_normals + ((size_t)b * OO + bi) * 6;
        float n0 = row[3], n1 = row[4], n2 = row[5];
        float r0 = row[0] - 0.002f * n0;
        float r1 = row[1] - 0.002f * n1;
        float r2 = row[2] - 0.002f * n2;
        float dp = n0 * (vx - r0) + n1 * (vy - r1) + n2 * (vz - r2);
        cp = fmaxf(-dp, 0.0f);
    }

    rd[tid] = cd;
    rp[tid] = cp;
    __syncthreads();
    for (int s = 128; s > 0; s >>= 1) {
        if (tid < s) {
            rd[tid] += rd[tid + s];
            rp[tid] += rp[tid + s];
        }
        __syncthreads();
    }
    if (tid == 0) {
        atomicAdd(&out[0], rd[0] * (1.0f / ((float)BB * VV * KNN)));
        atomicAdd(&out[1], rp[0] * (1.0f / ((float)BB * VV)));
    }
}

template <int LOGP>
static void launch_all(const float* verts, const float* anchor_verts,
                       const float* obj_pts, const float* contact_gaussians,
                       const float* obj_normals, const float* init_verts,
                       const float* init_anchors, int* gid_ws, float* active_ws,
                       float* segmn, float* segmx, float* w_ws, float* top5,
                       unsigned long long* pmin, float* out, hipStream_t stream) {
    constexpr int P = 1 << LOGP;
    constexpr int NCH = (VV + 63) / 64;
    hipLaunchKernelGGL((scan_kernel<LOGP>), dim3(BB * 2 * P + BB + 1), dim3(TSCAN),
                       0, stream, verts, anchor_verts, obj_pts, contact_gaussians,
                       obj_normals, init_verts, init_anchors, gid_ws, active_ws,
                       segmn, segmx, w_ws, top5, pmin, out);
    hipLaunchKernelGGL((finalize_kernel<LOGP>), dim3(BB * NCH), dim3(256), 0, stream,
                       top5, pmin, obj_normals, verts, gid_ws, w_ws, segmn,
                       segmx, active_ws, out);
}

extern "C" void kernel_launch(void* const* d_in, const int* in_sizes, int n_in,
                              void* d_out, int out_size, void* d_ws, size_t ws_size,
                              hipStream_t stream) {
    const float* verts = (const float*)d_in[0];
    const float* anchor_verts = (const float*)d_in[1];
    const float* obj_pts = (const float*)d_in[2];
    const float* contact_gaussians = (const float*)d_in[3];
    const float* obj_normals = (const float*)d_in[4];
    const float* init_verts = (const float*)d_in[5];
    const float* init_anchors = (const float*)d_in[6];
    float* out = (float*)d_out;

    char* ws = (char*)d_ws;
    int* gid_ws = (int*)(ws + 0);                       // 778 i  -> 4096
    float* active_ws = (float*)(ws + 4096);             // 32 f   -> 4224
    float* segmn = (float*)(ws + 4224);                 // 512 f  -> 6272
    float* segmx = (float*)(ws + 6272);                 // 512 f  -> 8320
    float* w_ws = (float*)(ws + 8320);                  // 12448 f-> 58112 (pad 58368)
    const size_t base = 58368;

    // P=16 (R1's P=32 regressed: occupancy unchanged, doubled writes).
    int logP = 4;
    while (logP > 0) {
        size_t need = base + (size_t)BB * (1 << logP) * VV * (KNN * 4 + 8);
        if (need <= ws_size) break;
        --logP;
    }

    unsigned long long* pmin = (unsigned long long*)(ws + base);
    float* top5 = (float*)(ws + base + (size_t)BB * ((size_t)1 << logP) * VV * 8);

#define LAUNCH(L)                                                              \
    launch_all<L>(verts, anchor_verts, obj_pts, contact_gaussians,             \
                  obj_normals, init_verts, init_anchors, gid_ws, active_ws,    \
                  segmn, segmx, w_ws, top5, pmin, out, stream)
    switch (logP) {
        case 4: LAUNCH(4); break;
        case 3: LAUNCH(3); break;
        case 2: LAUNCH(2); break;
        case 1: LAUNCH(1); break;
        default: LAUNCH(0); break;
    }
#undef LAUNCH
}

// Round 10
// 130.945 us; speedup vs baseline: 1.4569x; 1.0115x over previous
//
#include <hip/hip_runtime.h>
#include <math.h>

#define BB 16
#define VV 778
#define OO 8192
#define GG 32
#define KNN 5
#define THREE_LOG2PI 5.513631199228036f
#define TSCAN 832   // 13 waves x 1 slot (R2's best-measured shape)

#define MED3 __builtin_amdgcn_fmed3f

// sorted ascending insert: t[j] = min(t[j], max(t[j-1], s)) == med3(s, t[j-1], t[j])
__device__ __forceinline__ void insert5_med3(float (&t)[KNN], float s) {
    t[4] = MED3(s, t[3], t[4]);
    t[3] = MED3(s, t[2], t[3]);
    t[2] = MED3(s, t[1], t[2]);
    t[1] = MED3(s, t[0], t[1]);
    t[0] = fminf(t[0], s);
}

// merge sorted ascending b[5] into sorted ascending m[5]: 15 ops
__device__ __forceinline__ void merge5_med3(float (&m)[KNN], const float (&b)[KNN]) {
    m[4] = MED3(b[0], m[3], m[4]);
    m[3] = MED3(b[0], m[2], m[3]);
    m[2] = MED3(b[0], m[1], m[2]);
    m[1] = MED3(b[0], m[0], m[1]);
    m[0] = fminf(m[0], b[0]);
    m[4] = MED3(b[1], m[3], m[4]);
    m[3] = MED3(b[1], m[2], m[3]);
    m[2] = MED3(b[1], m[1], m[2]);
    m[1] = fminf(m[1], b[1]);
    m[4] = MED3(b[2], m[3], m[4]);
    m[3] = MED3(b[2], m[2], m[3]);
    m[2] = fminf(m[2], b[2]);
    m[4] = MED3(b[3], m[3], m[4]);
    m[3] = fminf(m[3], b[3]);
    m[4] = fminf(m[4], b[4]);
}

// monotone float->uint key: a<b <=> fkey(a)<fkey(b)
__device__ __forceinline__ unsigned int fkey(float s) {
    unsigned int u = __float_as_uint(s);
    unsigned int m = (u & 0x80000000u) ? 0xFFFFFFFFu : 0x80000000u;
    return u ^ m;
}

// ---------------- Kernel A: two block families, 832 thr x 1 vertex slot ----
// R8: R2 measured AT its LDS return-BW roofline (3.49 GB broadcast float4
// reads / 69 TB/s = 50.6us ~= 52.4 measured; VALU 21us hides underneath).
// Cut delivered bytes 25%: tile stores PACKED xyz (12 B/pt); inner loop
// reads 3x ds_read_b128 per 4 points (full-width issue, 768 B/pt/wave
// delivered). Distance via direct d2=(q-v)^2 (11 VALU/pt fam1, 9 fam2 -
// still under the 38us LDS floor). fam1 staging = straight float4 copy of
// the packed stream (16B-aligned at all chunk offsets). d2-form finalize
// (no +vv) and d2-based fkey already harness-validated in R5/R7.
template <int LOGP>
__global__ __launch_bounds__(TSCAN) void scan_kernel(
    const float* __restrict__ verts,
    const float* __restrict__ anchor_verts,
    const float* __restrict__ obj_pts,
    const float* __restrict__ contact_gaussians,
    const float* __restrict__ obj_normals,
    const float* __restrict__ init_verts,
    const float* __restrict__ init_anchors,
    int* __restrict__ gid_ws,
    float* __restrict__ active_ws,
    float* __restrict__ segmn,
    float* __restrict__ segmx,
    float* __restrict__ w_ws,
    float* __restrict__ top5,                 // [B][P][KNN][VV]  (d^2 values)
    unsigned long long* __restrict__ pmin,    // [B][P][VV] (fkey<<32)|idx
    float* __restrict__ out) {
    constexpr int P = 1 << LOGP;
    constexpr int NPTS = OO >> LOGP;
    constexpr int CH = (NPTS < 512) ? NPTS : 512;

    __shared__ float4 tp[(CH * 3) / 4];       // packed xyz: 3 float4 per 4 pts
    __shared__ float anc[GG * 4];
    __shared__ float cholb[GG * 10];
    __shared__ unsigned short gidl[VV];
    __shared__ unsigned int smn[GG], smx[GG];

    int tid = threadIdx.x;
    int bid = blockIdx.x;

    if (bid < BB * P) {
        // ================= Family 1: KNN top-5 =============================
        int p = bid & (P - 1);
        int b = bid >> LOGP;

        bool valid = tid < VV;
        int vc = valid ? tid : (VV - 1);
        float vx, vy, vz;
        {
            const float* vp = verts + ((size_t)b * VV + vc) * 3;
            vx = vp[0]; vy = vp[1]; vz = vp[2];
        }

        float t[KNN];
#pragma unroll
        for (int k = 0; k < KNN; ++k) t[k] = INFINITY;

        const float* pb = obj_pts + ((size_t)b * OO + (size_t)p * NPTS) * 3;
        for (int c0 = 0; c0 < NPTS; c0 += CH) {
            if (c0 != 0) __syncthreads();   // block-uniform; multi-chunk only
            // packed copy: CH*3/4 float4s, 16B-aligned (offset c0*12 % 16 == 0)
            const float4* gp = (const float4*)(pb + (size_t)c0 * 3);
            for (int j = tid; j < (CH * 3) / 4; j += TSCAN) tp[j] = gp[j];
            __syncthreads();
#pragma unroll 4
            for (int j = 0; j < CH / 4; ++j) {
                float4 A = tp[3 * j + 0];
                float4 B = tp[3 * j + 1];
                float4 C = tp[3 * j + 2];
                // p0=(A.x,A.y,A.z) p1=(A.w,B.x,B.y) p2=(B.z,B.w,C.x) p3=(C.y,C.z,C.w)
                {
                    float dx = A.x - vx, dy = A.y - vy, dz = A.z - vz;
                    insert5_med3(t, fmaf(dx, dx, fmaf(dy, dy, dz * dz)));
                }
                {
                    float dx = A.w - vx, dy = B.x - vy, dz = B.y - vz;
                    insert5_med3(t, fmaf(dx, dx, fmaf(dy, dy, dz * dz)));
                }
                {
                    float dx = B.z - vx, dy = B.w - vy, dz = C.x - vz;
                    insert5_med3(t, fmaf(dx, dx, fmaf(dy, dy, dz * dz)));
                }
                {
                    float dx = C.y - vx, dy = C.z - vy, dz = C.w - vz;
                    insert5_med3(t, fmaf(dx, dx, fmaf(dy, dy, dz * dz)));
                }
            }
        }
        if (valid) {
            size_t base = ((size_t)(b * P + p) * KNN) * VV + tid;
#pragma unroll
            for (int k = 0; k < KNN; ++k)
                top5[base + (size_t)k * VV] = t[k];
        }
        return;
    }

    // ================= Family 2: NN argmin (+ duties) ======================
    {
        int sub = bid - BB * P;
        int p = sub & (P - 1);
        int b = sub >> LOGP;

        bool wduty = (p == 0);                    // 16 blocks, one per b
        bool aduty = (p == 1 && b == 0);          // 1 block
        if (wduty || aduty) {
            if (tid < GG) {
                float x = init_anchors[tid * 3 + 0];
                float y = init_anchors[tid * 3 + 1];
                float z = init_anchors[tid * 3 + 2];
                anc[tid * 4 + 0] = x; anc[tid * 4 + 1] = y;
                anc[tid * 4 + 2] = z; anc[tid * 4 + 3] = x * x + y * y + z * z;
                smn[tid] = 0x7F800000u;
                smx[tid] = 0u;
                if (wduty) {
                    const float* cg2 = contact_gaussians + ((size_t)b * GG + tid) * 12;
                    const float* av = anchor_verts + ((size_t)b * GG + tid) * 3;
                    float c00 = cg2[3];
                    float c10 = cg2[6], c11 = cg2[7];
                    float c20 = cg2[9], c21 = cg2[10], c22 = cg2[11];
                    float L00 = sqrtf(c00);
                    float L10 = c10 / L00;
                    float L20 = c20 / L00;
                    float L11 = sqrtf(c11 - L10 * L10);
                    float L21 = (c21 - L20 * L10) / L11;
                    float L22 = sqrtf(c22 - L20 * L20 - L21 * L21);
                    float* c = cholb + tid * 10;
                    c[0] = L00; c[1] = L10; c[2] = L11;
                    c[3] = L20; c[4] = L21; c[5] = L22;
                    c[6] = logf(L00) + logf(L11) + logf(L22);
                    c[7] = cg2[0] + av[0];
                    c[8] = cg2[1] + av[1];
                    c[9] = cg2[2] + av[2];
                }
            }
            __syncthreads();
            for (int v = tid; v < VV; v += TSCAN) {
                float x = init_verts[v * 3 + 0];
                float y = init_verts[v * 3 + 1];
                float z = init_verts[v * 3 + 2];
                float vv = x * x + y * y + z * z;
                float best = INFINITY;
                int bg = 0;
                for (int g = 0; g < GG; ++g) {
                    float d2 = vv + anc[g * 4 + 3] -
                               2.0f * (x * anc[g * 4 + 0] + y * anc[g * 4 + 1] + z * anc[g * 4 + 2]);
                    d2 = fmaxf(d2, 0.0f);
                    if (d2 < best) { best = d2; bg = g; }
                }
                gidl[v] = (unsigned short)bg;
                if (aduty) gid_ws[v] = bg;
            }
            __syncthreads();
            if (wduty) {
                for (int v = tid; v < VV; v += TSCAN) {
                    int g = gidl[v];
                    const float* c = cholb + g * 10;
                    const float* vp = verts + ((size_t)b * VV + v) * 3;
                    float d0 = vp[0] - c[7];
                    float d1 = vp[1] - c[8];
                    float d2 = vp[2] - c[9];
                    float y0 = d0 / c[0];
                    float y1 = (d1 - c[1] * y0) / c[2];
                    float y2 = (d2 - c[3] * y0 - c[4] * y1) / c[5];
                    float maha = y0 * y0 + y1 * y1 + y2 * y2;
                    float wv = expf(-0.5f * (maha + THREE_LOG2PI) - c[6]);
                    w_ws[(size_t)b * VV + v] = wv;
                    unsigned int u = __float_as_uint(wv);
                    atomicMin(&smn[g], u);
                    atomicMax(&smx[g], u);
                }
                __syncthreads();
                if (tid < GG) {
                    segmn[b * GG + tid] = __uint_as_float(smn[tid]);
                    segmx[b * GG + tid] = __uint_as_float(smx[tid]);
                }
            }
            if (aduty) {
                if (tid < GG) {
                    int any = 0;
                    for (int bb = 0; bb < BB && !any; ++bb) {
                        for (int c = 0; c < 12; ++c) {
                            if (fabsf(contact_gaussians[((size_t)bb * GG + tid) * 12 + c]) > 1e-9f) {
                                any = 1;
                                break;
                            }
                        }
                    }
                    active_ws[tid] = any ? 1.0f : 0.0f;
                }
                if (tid == 0) { out[0] = 0.0f; out[1] = 0.0f; }
            }
            __syncthreads();
        }

        bool valid = tid < VV;
        int vc = valid ? tid : (VV - 1);
        float vx, vy, vz;
        {
            const float* vp = verts + ((size_t)b * VV + vc) * 3;
            vx = vp[0]; vy = vp[1]; vz = vp[2];
        }

        float bsv = INFINITY;
        int biv = 0;

        const float* nbp = obj_normals + ((size_t)b * OO + (size_t)p * NPTS) * 6;
        float* t3 = (float*)tp;
        for (int c0 = 0; c0 < NPTS; c0 += CH) {
            if (c0 != 0) __syncthreads();
            for (int j = tid; j < CH; j += TSCAN) {
                const float* r = nbp + (size_t)(c0 + j) * 6;
                t3[3 * j + 0] = r[0];
                t3[3 * j + 1] = r[1];
                t3[3 * j + 2] = r[2];
            }
            __syncthreads();
#pragma unroll 4
            for (int j = 0; j < CH / 4; ++j) {
                float4 A = tp[3 * j + 0];
                float4 B = tp[3 * j + 1];
                float4 C = tp[3 * j + 2];
                int gi = c0 + 4 * j;
                {
                    float dx = A.x - vx, dy = A.y - vy, dz = A.z - vz;
                    float u = fmaf(dx, dx, fmaf(dy, dy, dz * dz));
                    if (u < bsv) { bsv = u; biv = gi; }
                }
                {
                    float dx = A.w - vx, dy = B.x - vy, dz = B.y - vz;
                    float u = fmaf(dx, dx, fmaf(dy, dy, dz * dz));
                    if (u < bsv) { bsv = u; biv = gi + 1; }
                }
                {
                    float dx = B.z - vx, dy = B.w - vy, dz = C.x - vz;
                    float u = fmaf(dx, dx, fmaf(dy, dy, dz * dz));
                    if (u < bsv) { bsv = u; biv = gi + 2; }
                }
                {
                    float dx = C.y - vx, dy = C.z - vy, dz = C.w - vz;
                    float u = fmaf(dx, dx, fmaf(dy, dy, dz * dz));
                    if (u < bsv) { bsv = u; biv = gi + 3; }
                }
            }
        }
        if (valid) {
            unsigned long long key =
                ((unsigned long long)fkey(bsv) << 32) |
                (unsigned int)(p * NPTS + biv);
            pmin[(size_t)(b * P + p) * VV + tid] = key;
        }
    }
}

// ---------------- Kernel B: tree merge + weights + reduce ------------------
// grid = BB * 13 blocks of 256. tid = pi*64 + vi.
// top5/pmin hold full d^2 (direct form) -> no +vv in the sqrt (R5-validated).
template <int LOGP>
__global__ __launch_bounds__(256) void finalize_kernel(
    const float* __restrict__ top5,
    const unsigned long long* __restrict__ pmin,
    const float* __restrict__ obj_normals,
    const float* __restrict__ verts,
    const int* __restrict__ gid,
    const float* __restrict__ w,
    const float* __restrict__ segmn,
    const float* __restrict__ segmx,
    const float* __restrict__ active,
    float* __restrict__ out) {
    constexpr int P = 1 << LOGP;
    constexpr int NM = (P + 3) / 4;
    constexpr int NCH = (VV + 63) / 64;

    __shared__ float mt[4][KNN][64];
    __shared__ unsigned long long at[4][64];
    __shared__ float rd[256], rp[256];

    int tid = threadIdx.x;
    int pi = tid >> 6;
    int vi = tid & 63;
    int b = blockIdx.x / NCH;
    int chunk = blockIdx.x - b * NCH;
    int v = chunk * 64 + vi;
    bool valid = v < VV;

    float m[KNN];
#pragma unroll
    for (int k = 0; k < KNN; ++k) m[k] = INFINITY;
    unsigned long long amin = 0xFFFFFFFFFFFFFFFFull;
    if (valid) {
#pragma unroll
        for (int r = 0; r < NM; ++r) {
            int p = pi * NM + r;
            if (p < P) {
                size_t base = ((size_t)(b * P + p) * KNN) * VV + v;
                float t[KNN];
#pragma unroll
                for (int k = 0; k < KNN; ++k) t[k] = top5[base + (size_t)k * VV];
                merge5_med3(m, t);
                unsigned long long a = pmin[(size_t)(b * P + p) * VV + v];
                if (a < amin) amin = a;
            }
        }
    }

#pragma unroll
    for (int k = 0; k < KNN; ++k) mt[pi][k][vi] = m[k];
    at[pi][vi] = amin;
    __syncthreads();

    if (pi < 2) {
        float t[KNN];
#pragma unroll
        for (int k = 0; k < KNN; ++k) t[k] = mt[pi + 2][k][vi];
        merge5_med3(m, t);
#pragma unroll
        for (int k = 0; k < KNN; ++k) mt[pi][k][vi] = m[k];
        unsigned long long a = at[pi + 2][vi];
        if (a < amin) amin = a;
        at[pi][vi] = amin;
    }
    __syncthreads();

    float cd = 0.0f, cp = 0.0f;
    if (pi == 0 && valid) {
        float t[KNN];
#pragma unroll
        for (int k = 0; k < KNN; ++k) t[k] = mt[1][k][vi];
        merge5_med3(m, t);
        unsigned long long a = at[1][vi];
        if (a < amin) amin = a;

        const float* vp = verts + ((size_t)b * VV + v) * 3;
        float vx = vp[0], vy = vp[1], vz = vp[2];

        int g = gid[v];
        float wv = w[(size_t)b * VV + v];
        float mn = segmn[b * GG + g];
        float mx = segmx[b * GG + g];
        float wn = (wv - mn) / (mx - mn);
        float eff = (active[g] != 0.0f && wn > 0.01f) ? wn : 0.0f;
        float sk = 0.0f;
#pragma unroll
        for (int k = 0; k < KNN; ++k) sk += sqrtf(fmaxf(m[k], 0.0f));
        cd = eff * sk;

        int bi = (int)(unsigned int)(amin & 0xFFFFFFFFull);
        const float* row = obj_normals + ((size_t)b * OO + bi) * 6;
        float n0 = row[3], n1 = row[4], n2 = row[5];
        float r0 = row[0] - 0.002f * n0;
        float r1 = row[1] - 0.002f * n1;
        float r2 = row[2] - 0.002f * n2;
        float dp = n0 * (vx - r0) + n1 * (vy - r1) + n2 * (vz - r2);
        cp = fmaxf(-dp, 0.0f);
    }

    rd[tid] = cd;
    rp[tid] = cp;
    __syncthreads();
    for (int s = 128; s > 0; s >>= 1) {
        if (tid < s) {
            rd[tid] += rd[tid + s];
            rp[tid] += rp[tid + s];
        }
        __syncthreads();
    }
    if (tid == 0) {
        atomicAdd(&out[0], rd[0] * (1.0f / ((float)BB * VV * KNN)));
        atomicAdd(&out[1], rp[0] * (1.0f / ((float)BB * VV)));
    }
}

template <int LOGP>
static void launch_all(const float* verts, const float* anchor_verts,
                       const float* obj_pts, const float* contact_gaussians,
                       const float* obj_normals, const float* init_verts,
                       const float* init_anchors, int* gid_ws, float* active_ws,
                       float* segmn, float* segmx, float* w_ws, float* top5,
                       unsigned long long* pmin, float* out, hipStream_t stream) {
    constexpr int P = 1 << LOGP;
    constexpr int NCH = (VV + 63) / 64;
    hipLaunchKernelGGL((scan_kernel<LOGP>), dim3(BB * 2 * P), dim3(TSCAN),
                       0, stream, verts, anchor_verts, obj_pts, contact_gaussians,
                       obj_normals, init_verts, init_anchors, gid_ws, active_ws,
                       segmn, segmx, w_ws, top5, pmin, out);
    hipLaunchKernelGGL((finalize_kernel<LOGP>), dim3(BB * NCH), dim3(256), 0, stream,
                       top5, pmin, obj_normals, verts, gid_ws, w_ws, segmn,
                       segmx, active_ws, out);
}

extern "C" void kernel_launch(void* const* d_in, const int* in_sizes, int n_in,
                              void* d_out, int out_size, void* d_ws, size_t ws_size,
                              hipStream_t stream) {
    const float* verts = (const float*)d_in[0];
    const float* anchor_verts = (const float*)d_in[1];
    const float* obj_pts = (const float*)d_in[2];
    const float* contact_gaussians = (const float*)d_in[3];
    const float* obj_normals = (const float*)d_in[4];
    const float* init_verts = (const float*)d_in[5];
    const float* init_anchors = (const float*)d_in[6];
    float* out = (float*)d_out;

    char* ws = (char*)d_ws;
    int* gid_ws = (int*)(ws + 0);                       // 778 i  -> 4096
    float* active_ws = (float*)(ws + 4096);             // 32 f   -> 4224
    float* segmn = (float*)(ws + 4224);                 // 512 f  -> 6272
    float* segmx = (float*)(ws + 6272);                 // 512 f  -> 8320
    float* w_ws = (float*)(ws + 8320);                  // 12448 f-> 58112 (pad 58368)
    const size_t base = 58368;

    // P=16 (R1's P=32 regressed: occupancy unchanged, doubled writes).
    int logP = 4;
    while (logP > 0) {
        size_t need = base + (size_t)BB * (1 << logP) * VV * (KNN * 4 + 8);
        if (need <= ws_size) break;
        --logP;
    }

    unsigned long long* pmin = (unsigned long long*)(ws + base);
    float* top5 = (float*)(ws + base + (size_t)BB * ((size_t)1 << logP) * VV * 8);

#define LAUNCH(L)                                                              \
    launch_all<L>(verts, anchor_verts, obj_pts, contact_gaussians,             \
                  obj_normals, init_verts, init_anchors, gid_ws, active_ws,    \
                  segmn, segmx, w_ws, top5, pmin, out, stream)
    switch (logP) {
        case 4: LAUNCH(4); break;
        case 3: LAUNCH(3); break;
        case 2: LAUNCH(2); break;
        case 1: LAUNCH(1); break;
        default: LAUNCH(0); break;
    }
#undef LAUNCH
}

// Round 11
// 123.254 us; speedup vs baseline: 1.5478x; 1.0624x over previous
//
#include <hip/hip_runtime.h>
#include <math.h>

#define BB 16
#define VV 778
#define OO 8192
#define GG 32
#define KNN 5
#define THREE_LOG2PI 5.513631199228036f
#define TSCAN 832   // 13 waves: covers 778 vertices with 1 slot/thread (6.5% pad)

#define MED3 __builtin_amdgcn_fmed3f

// sorted ascending insert: t[j] = min(t[j], max(t[j-1], s)) == med3(s, t[j-1], t[j])
__device__ __forceinline__ void insert5_med3(float (&t)[KNN], float s) {
    t[4] = MED3(s, t[3], t[4]);
    t[3] = MED3(s, t[2], t[3]);
    t[2] = MED3(s, t[1], t[2]);
    t[1] = MED3(s, t[0], t[1]);
    t[0] = fminf(t[0], s);
}

// merge sorted ascending b[5] into sorted ascending m[5]: 15 ops
__device__ __forceinline__ void merge5_med3(float (&m)[KNN], const float (&b)[KNN]) {
    m[4] = MED3(b[0], m[3], m[4]);
    m[3] = MED3(b[0], m[2], m[3]);
    m[2] = MED3(b[0], m[1], m[2]);
    m[1] = MED3(b[0], m[0], m[1]);
    m[0] = fminf(m[0], b[0]);
    m[4] = MED3(b[1], m[3], m[4]);
    m[3] = MED3(b[1], m[2], m[3]);
    m[2] = MED3(b[1], m[1], m[2]);
    m[1] = fminf(m[1], b[1]);
    m[4] = MED3(b[2], m[3], m[4]);
    m[3] = MED3(b[2], m[2], m[3]);
    m[2] = fminf(m[2], b[2]);
    m[4] = MED3(b[3], m[3], m[4]);
    m[3] = fminf(m[3], b[3]);
    m[4] = fminf(m[4], b[4]);
}

// monotone float->uint key: a<b <=> fkey(a)<fkey(b)
__device__ __forceinline__ unsigned int fkey(float s) {
    unsigned int u = __float_as_uint(s);
    unsigned int m = (u & 0x80000000u) ? 0xFFFFFFFFu : 0x80000000u;
    return u ^ m;
}

// ---------------- Kernel A: two block families, 832 thr x 1 vertex slot ----
// FINAL (R10 revert to R2, session best: 123.88us total, scan 52.4us).
// 10-round ablation: R2's float4+w LDS broadcast delivers 3.49 GB at
// 66.6 TB/s = 97% of the 69 TB/s LDS ceiling; VALU (~21us) hides under it.
// All alternative delivery mechanisms regressed: 4-slot 56.3, 2-slot 70.5,
// compiler-scalar 64.4, forced SMEM 130+, readlane 86.0, rotation 63.2,
// packed-12B 60.7 (byte cut raised VALU above the LDS floor). This
// configuration is the measured LDS-broadcast roofline for the exhaustive
// 778x8192 exact top-5/argmin scan.
template <int LOGP>
__global__ __launch_bounds__(TSCAN) void scan_kernel(
    const float* __restrict__ verts,
    const float* __restrict__ anchor_verts,
    const float* __restrict__ obj_pts,
    const float* __restrict__ contact_gaussians,
    const float* __restrict__ obj_normals,
    const float* __restrict__ init_verts,
    const float* __restrict__ init_anchors,
    int* __restrict__ gid_ws,
    float* __restrict__ active_ws,
    float* __restrict__ segmn,
    float* __restrict__ segmx,
    float* __restrict__ w_ws,
    float* __restrict__ top5,                 // [B][P][KNN][VV]
    unsigned long long* __restrict__ pmin,    // [B][P][VV] (fkey<<32)|idx
    float* __restrict__ out) {
    constexpr int P = 1 << LOGP;
    constexpr int NPTS = OO >> LOGP;
    constexpr int CH = (NPTS < 512) ? NPTS : 512;

    __shared__ float4 tile[CH];
    __shared__ float anc[GG * 4];
    __shared__ float cholb[GG * 10];
    __shared__ unsigned short gidl[VV];
    __shared__ unsigned int smn[GG], smx[GG];

    int tid = threadIdx.x;
    int bid = blockIdx.x;

    if (bid < BB * P) {
        // ================= Family 1: KNN top-5 =============================
        int p = bid & (P - 1);
        int b = bid >> LOGP;

        bool valid = tid < VV;
        int vc = valid ? tid : (VV - 1);
        float X, Y, Z;
        {
            const float* vp = verts + ((size_t)b * VV + vc) * 3;
            X = -2.0f * vp[0];
            Y = -2.0f * vp[1];
            Z = -2.0f * vp[2];
        }

        float t[KNN];
#pragma unroll
        for (int k = 0; k < KNN; ++k) t[k] = INFINITY;

        const float* pb = obj_pts + ((size_t)b * OO + p * NPTS) * 3;
        for (int c0 = 0; c0 < NPTS; c0 += CH) {
            if (c0 != 0) __syncthreads();   // block-uniform; multi-chunk only
            for (int j = tid; j < CH; j += TSCAN) {
                const float* q = pb + (size_t)(c0 + j) * 3;
                float a0 = q[0], a1 = q[1], a2 = q[2];
                tile[j] = make_float4(a0, a1, a2, a0 * a0 + a1 * a1 + a2 * a2);
            }
            __syncthreads();
#pragma unroll 8
            for (int i = 0; i < CH; ++i) {
                float4 q = tile[i];
                float sv = fmaf(X, q.x, fmaf(Y, q.y, fmaf(Z, q.z, q.w)));
                insert5_med3(t, sv);
            }
        }
        if (valid) {
            size_t base = ((size_t)(b * P + p) * KNN) * VV + tid;
#pragma unroll
            for (int k = 0; k < KNN; ++k)
                top5[base + (size_t)k * VV] = t[k];
        }
        return;
    }

    // ================= Family 2: NN argmin (+ duties) ======================
    {
        int sub = bid - BB * P;
        int p = sub & (P - 1);
        int b = sub >> LOGP;

        bool wduty = (p == 0);                    // 16 blocks, one per b
        bool aduty = (p == 1 && b == 0);          // 1 block
        if (wduty || aduty) {
            if (tid < GG) {
                float x = init_anchors[tid * 3 + 0];
                float y = init_anchors[tid * 3 + 1];
                float z = init_anchors[tid * 3 + 2];
                anc[tid * 4 + 0] = x; anc[tid * 4 + 1] = y;
                anc[tid * 4 + 2] = z; anc[tid * 4 + 3] = x * x + y * y + z * z;
                smn[tid] = 0x7F800000u;
                smx[tid] = 0u;
                if (wduty) {
                    const float* cg2 = contact_gaussians + ((size_t)b * GG + tid) * 12;
                    const float* av = anchor_verts + ((size_t)b * GG + tid) * 3;
                    float c00 = cg2[3];
                    float c10 = cg2[6], c11 = cg2[7];
                    float c20 = cg2[9], c21 = cg2[10], c22 = cg2[11];
                    float L00 = sqrtf(c00);
                    float L10 = c10 / L00;
                    float L20 = c20 / L00;
                    float L11 = sqrtf(c11 - L10 * L10);
                    float L21 = (c21 - L20 * L10) / L11;
                    float L22 = sqrtf(c22 - L20 * L20 - L21 * L21);
                    float* c = cholb + tid * 10;
                    c[0] = L00; c[1] = L10; c[2] = L11;
                    c[3] = L20; c[4] = L21; c[5] = L22;
                    c[6] = logf(L00) + logf(L11) + logf(L22);
                    c[7] = cg2[0] + av[0];
                    c[8] = cg2[1] + av[1];
                    c[9] = cg2[2] + av[2];
                }
            }
            __syncthreads();
            for (int v = tid; v < VV; v += TSCAN) {
                float x = init_verts[v * 3 + 0];
                float y = init_verts[v * 3 + 1];
                float z = init_verts[v * 3 + 2];
                float vv = x * x + y * y + z * z;
                float best = INFINITY;
                int bg = 0;
                for (int g = 0; g < GG; ++g) {
                    float d2 = vv + anc[g * 4 + 3] -
                               2.0f * (x * anc[g * 4 + 0] + y * anc[g * 4 + 1] + z * anc[g * 4 + 2]);
                    d2 = fmaxf(d2, 0.0f);
                    if (d2 < best) { best = d2; bg = g; }
                }
                gidl[v] = (unsigned short)bg;
                if (aduty) gid_ws[v] = bg;
            }
            __syncthreads();
            if (wduty) {
                for (int v = tid; v < VV; v += TSCAN) {
                    int g = gidl[v];
                    const float* c = cholb + g * 10;
                    const float* vp = verts + ((size_t)b * VV + v) * 3;
                    float d0 = vp[0] - c[7];
                    float d1 = vp[1] - c[8];
                    float d2 = vp[2] - c[9];
                    float y0 = d0 / c[0];
                    float y1 = (d1 - c[1] * y0) / c[2];
                    float y2 = (d2 - c[3] * y0 - c[4] * y1) / c[5];
                    float maha = y0 * y0 + y1 * y1 + y2 * y2;
                    float wv = expf(-0.5f * (maha + THREE_LOG2PI) - c[6]);
                    w_ws[(size_t)b * VV + v] = wv;
                    unsigned int u = __float_as_uint(wv);
                    atomicMin(&smn[g], u);
                    atomicMax(&smx[g], u);
                }
                __syncthreads();
                if (tid < GG) {
                    segmn[b * GG + tid] = __uint_as_float(smn[tid]);
                    segmx[b * GG + tid] = __uint_as_float(smx[tid]);
                }
            }
            if (aduty) {
                if (tid < GG) {
                    int any = 0;
                    for (int bb = 0; bb < BB && !any; ++bb) {
                        for (int c = 0; c < 12; ++c) {
                            if (fabsf(contact_gaussians[((size_t)bb * GG + tid) * 12 + c]) > 1e-9f) {
                                any = 1;
                                break;
                            }
                        }
                    }
                    active_ws[tid] = any ? 1.0f : 0.0f;
                }
                if (tid == 0) { out[0] = 0.0f; out[1] = 0.0f; }
            }
            __syncthreads();
        }

        bool valid = tid < VV;
        int vc = valid ? tid : (VV - 1);
        float X, Y, Z;
        {
            const float* vp = verts + ((size_t)b * VV + vc) * 3;
            X = -2.0f * vp[0];
            Y = -2.0f * vp[1];
            Z = -2.0f * vp[2];
        }

        float bsv = INFINITY;
        int biv = 0;

        const float* nbp = obj_normals + ((size_t)b * OO + p * NPTS) * 6;
        for (int c0 = 0; c0 < NPTS; c0 += CH) {
            if (c0 != 0) __syncthreads();
            for (int j = tid; j < CH; j += TSCAN) {
                const float* r = nbp + (size_t)(c0 + j) * 6;
                float b0 = r[0], b1 = r[1], b2 = r[2];
                tile[j] = make_float4(b0, b1, b2, b0 * b0 + b1 * b1 + b2 * b2);
            }
            __syncthreads();
#pragma unroll 8
            for (int i = 0; i < CH; ++i) {
                float4 n = tile[i];
                float u = fmaf(X, n.x, fmaf(Y, n.y, fmaf(Z, n.z, n.w)));
                if (u < bsv) { bsv = u; biv = c0 + i; }
            }
        }
        if (valid) {
            unsigned long long key =
                ((unsigned long long)fkey(bsv) << 32) |
                (unsigned int)(p * NPTS + biv);
            pmin[(size_t)(b * P + p) * VV + tid] = key;
        }
    }
}

// ---------------- Kernel B: tree merge + weights + reduce ------------------
// grid = BB * 13 blocks of 256. tid = pi*64 + vi.
template <int LOGP>
__global__ __launch_bounds__(256) void finalize_kernel(
    const float* __restrict__ top5,
    const unsigned long long* __restrict__ pmin,
    const float* __restrict__ obj_normals,
    const float* __restrict__ verts,
    const int* __restrict__ gid,
    const float* __restrict__ w,
    const float* __restrict__ segmn,
    const float* __restrict__ segmx,
    const float* __restrict__ active,
    float* __restrict__ out) {
    constexpr int P = 1 << LOGP;
    constexpr int NM = (P + 3) / 4;
    constexpr int NCH = (VV + 63) / 64;

    __shared__ float mt[4][KNN][64];
    __shared__ unsigned long long at[4][64];
    __shared__ float rd[256], rp[256];

    int tid = threadIdx.x;
    int pi = tid >> 6;
    int vi = tid & 63;
    int b = blockIdx.x / NCH;
    int chunk = blockIdx.x - b * NCH;
    int v = chunk * 64 + vi;
    bool valid = v < VV;

    float m[KNN];
#pragma unroll
    for (int k = 0; k < KNN; ++k) m[k] = INFINITY;
    unsigned long long amin = 0xFFFFFFFFFFFFFFFFull;
    if (valid) {
#pragma unroll
        for (int r = 0; r < NM; ++r) {
            int p = pi * NM + r;
            if (p < P) {
                size_t base = ((size_t)(b * P + p) * KNN) * VV + v;
                float t[KNN];
#pragma unroll
                for (int k = 0; k < KNN; ++k) t[k] = top5[base + (size_t)k * VV];
                merge5_med3(m, t);
                unsigned long long a = pmin[(size_t)(b * P + p) * VV + v];
                if (a < amin) amin = a;
            }
        }
    }

#pragma unroll
    for (int k = 0; k < KNN; ++k) mt[pi][k][vi] = m[k];
    at[pi][vi] = amin;
    __syncthreads();

    if (pi < 2) {
        float t[KNN];
#pragma unroll
        for (int k = 0; k < KNN; ++k) t[k] = mt[pi + 2][k][vi];
        merge5_med3(m, t);
#pragma unroll
        for (int k = 0; k < KNN; ++k) mt[pi][k][vi] = m[k];
        unsigned long long a = at[pi + 2][vi];
        if (a < amin) amin = a;
        at[pi][vi] = amin;
    }
    __syncthreads();

    float cd = 0.0f, cp = 0.0f;
    if (pi == 0 && valid) {
        float t[KNN];
#pragma unroll
        for (int k = 0; k < KNN; ++k) t[k] = mt[1][k][vi];
        merge5_med3(m, t);
        unsigned long long a = at[1][vi];
        if (a < amin) amin = a;

        const float* vp = verts + ((size_t)b * VV + v) * 3;
        float vx = vp[0], vy = vp[1], vz = vp[2];
        float vv = vx * vx + vy * vy + vz * vz;

        int g = gid[v];
        float wv = w[(size_t)b * VV + v];
        float mn = segmn[b * GG + g];
        float mx = segmx[b * GG + g];
        float wn = (wv - mn) / (mx - mn);
        float eff = (active[g] != 0.0f && wn > 0.01f) ? wn : 0.0f;
        float sk = 0.0f;
#pragma unroll
        for (int k = 0; k < KNN; ++k) sk += sqrtf(fmaxf(vv + m[k], 0.0f));
        cd = eff * sk;

        int bi = (int)(unsigned int)(amin & 0xFFFFFFFFull);
        const float* row = obj_normals + ((size_t)b * OO + bi) * 6;
        float n0 = row[3], n1 = row[4], n2 = row[5];
        float r0 = row[0] - 0.002f * n0;
        float r1 = row[1] - 0.002f * n1;
        float r2 = row[2] - 0.002f * n2;
        float dp = n0 * (vx - r0) + n1 * (vy - r1) + n2 * (vz - r2);
        cp = fmaxf(-dp, 0.0f);
    }

    rd[tid] = cd;
    rp[tid] = cp;
    __syncthreads();
    for (int s = 128; s > 0; s >>= 1) {
        if (tid < s) {
            rd[tid] += rd[tid + s];
            rp[tid] += rp[tid + s];
        }
        __syncthreads();
    }
    if (tid == 0) {
        atomicAdd(&out[0], rd[0] * (1.0f / ((float)BB * VV * KNN)));
        atomicAdd(&out[1], rp[0] * (1.0f / ((float)BB * VV)));
    }
}

template <int LOGP>
static void launch_all(const float* verts, const float* anchor_verts,
                       const float* obj_pts, const float* contact_gaussians,
                       const float* obj_normals, const float* init_verts,
                       const float* init_anchors, int* gid_ws, float* active_ws,
                       float* segmn, float* segmx, float* w_ws, float* top5,
                       unsigned long long* pmin, float* out, hipStream_t stream) {
    constexpr int P = 1 << LOGP;
    constexpr int NCH = (VV + 63) / 64;
    hipLaunchKernelGGL((scan_kernel<LOGP>), dim3(BB * 2 * P), dim3(TSCAN),
                       0, stream, verts, anchor_verts, obj_pts, contact_gaussians,
                       obj_normals, init_verts, init_anchors, gid_ws, active_ws,
                       segmn, segmx, w_ws, top5, pmin, out);
    hipLaunchKernelGGL((finalize_kernel<LOGP>), dim3(BB * NCH), dim3(256), 0, stream,
                       top5, pmin, obj_normals, verts, gid_ws, w_ws, segmn,
                       segmx, active_ws, out);
}

extern "C" void kernel_launch(void* const* d_in, const int* in_sizes, int n_in,
                              void* d_out, int out_size, void* d_ws, size_t ws_size,
                              hipStream_t stream) {
    const float* verts = (const float*)d_in[0];
    const float* anchor_verts = (const float*)d_in[1];
    const float* obj_pts = (const float*)d_in[2];
    const float* contact_gaussians = (const float*)d_in[3];
    const float* obj_normals = (const float*)d_in[4];
    const float* init_verts = (const float*)d_in[5];
    const float* init_anchors = (const float*)d_in[6];
    float* out = (float*)d_out;

    char* ws = (char*)d_ws;
    int* gid_ws = (int*)(ws + 0);                       // 778 i  -> 4096
    float* active_ws = (float*)(ws + 4096);             // 32 f   -> 4224
    float* segmn = (float*)(ws + 4224);                 // 512 f  -> 6272
    float* segmx = (float*)(ws + 6272);                 // 512 f  -> 8320
    float* w_ws = (float*)(ws + 8320);                  // 12448 f-> 58112 (pad 58368)
    const size_t base = 58368;

    // P=16 (R1's P=32 regressed: occupancy unchanged, doubled writes).
    int logP = 4;
    while (logP > 0) {
        size_t need = base + (size_t)BB * (1 << logP) * VV * (KNN * 4 + 8);
        if (need <= ws_size) break;
        --logP;
    }

    unsigned long long* pmin = (unsigned long long*)(ws + base);
    float* top5 = (float*)(ws + base + (size_t)BB * ((size_t)1 << logP) * VV * 8);

#define LAUNCH(L)                                                              \
    launch_all<L>(verts, anchor_verts, obj_pts, contact_gaussians,             \
                  obj_normals, init_verts, init_anchors, gid_ws, active_ws,    \
                  segmn, segmx, w_ws, top5, pmin, out, stream)
    switch (logP) {
        case 4: LAUNCH(4); break;
        case 3: LAUNCH(3); break;
        case 2: LAUNCH(2); break;
        case 1: LAUNCH(1); break;
        default: LAUNCH(0); break;
    }
#undef LAUNCH
}